// Round 1
// baseline (960.511 us; speedup 1.0000x reference)
//
#include <hip/hip_runtime.h>
#include <stdint.h>

typedef short v8s __attribute__((ext_vector_type(8)));   // 8 bf16 (4 VGPRs)
typedef float v4f __attribute__((ext_vector_type(4)));   // 16x16 C/D frag

__device__ __forceinline__ unsigned short f2bf(float f) {
    union { float f; uint32_t u; } x; x.f = f;
    uint32_t r = (x.u + 0x7fffu + ((x.u >> 16) & 1u)) >> 16;
    return (unsigned short)r;
}

// ---------------- fp32 -> bf16 cast (memory-bound) ----------------
__global__ __launch_bounds__(256) void cast_f32_bf16(const float* __restrict__ in,
                                                     unsigned short* __restrict__ out, int n) {
    int i = (blockIdx.x * 256 + threadIdx.x) * 4;
    const int stride = gridDim.x * 256 * 4;
    for (; i < n; i += stride) {
        float4 v = *(const float4*)(in + i);
        ushort4 o;
        o.x = f2bf(v.x); o.y = f2bf(v.y); o.z = f2bf(v.z); o.w = f2bf(v.w);
        *(ushort4*)(out + i) = o;
    }
}

// ---------------- NT GEMM: C[M,N] = A[M,K] * B[N,K]^T + bias ----------------
// 128x128 tile, BK=64, 256 thr (4 waves, 2x2 of 64x64), 16x16x32 bf16 MFMA,
// global_load_lds width-16 staging with XOR-swizzled 16B chunks (2-way LDS conflicts only).
template <bool OUT_F32>
__global__ __launch_bounds__(256) void gemm_nt(const unsigned short* __restrict__ A,
                                               const unsigned short* __restrict__ B,
                                               const float* __restrict__ bias,
                                               void* __restrict__ Cout,
                                               int M, int N, int K) {
    __shared__ unsigned short As[128 * 64];
    __shared__ unsigned short Bs[128 * 64];
    const int tid = threadIdx.x;
    const int wv = tid >> 6, lane = tid & 63;
    const int quad = lane >> 4, l16 = lane & 15;
    const int tiles_n = N >> 7;
    const int tm = blockIdx.x / tiles_n, tn = blockIdx.x - tm * tiles_n;
    const int m0 = tm << 7, n0 = tn << 7;
    const int wr = (wv >> 1) * 64, wc = (wv & 1) * 64;

    v4f acc[4][4] = {};

    for (int k0 = 0; k0 < K; k0 += 64) {
        __syncthreads();
#pragma unroll
        for (int j = 0; j < 4; ++j) {
            const int cb = (wv * 4 + j) * 64;          // wave-uniform chunk base
            const int cl = cb + lane;                  // this lane's dest chunk
            const int row = cl >> 3;
            const int kc = (cl & 7) ^ (row & 7);       // swizzled source chunk
            const unsigned short* ga = A + (size_t)(m0 + row) * K + k0 + kc * 8;
            const unsigned short* gb = B + (size_t)(n0 + row) * K + k0 + kc * 8;
            __builtin_amdgcn_global_load_lds(
                (const __attribute__((address_space(1))) unsigned int*)ga,
                (__attribute__((address_space(3))) unsigned int*)(As + cb * 8), 16, 0, 0);
            __builtin_amdgcn_global_load_lds(
                (const __attribute__((address_space(1))) unsigned int*)gb,
                (__attribute__((address_space(3))) unsigned int*)(Bs + cb * 8), 16, 0, 0);
        }
        __syncthreads();   // drains vmcnt: tiles resident in LDS
#pragma unroll
        for (int ks = 0; ks < 2; ++ks) {
            v8s af[4], bf[4];
#pragma unroll
            for (int mt = 0; mt < 4; ++mt) {
                const int row = wr + mt * 16 + l16;
                const int ch = row * 8 + ((ks * 4 + quad) ^ (row & 7));
                af[mt] = *(const v8s*)(As + ch * 8);
            }
#pragma unroll
            for (int nt = 0; nt < 4; ++nt) {
                const int row = wc + nt * 16 + l16;
                const int ch = row * 8 + ((ks * 4 + quad) ^ (row & 7));
                bf[nt] = *(const v8s*)(Bs + ch * 8);
            }
#pragma unroll
            for (int mt = 0; mt < 4; ++mt)
#pragma unroll
                for (int nt = 0; nt < 4; ++nt)
                    acc[mt][nt] = __builtin_amdgcn_mfma_f32_16x16x32_bf16(
                        af[mt], bf[nt], acc[mt][nt], 0, 0, 0);
        }
    }
    // epilogue: bias + store (C/D layout: col=lane&15, row=quad*4+reg)
#pragma unroll
    for (int nt = 0; nt < 4; ++nt) {
        const int col = n0 + wc + nt * 16 + l16;
        const float bv = bias[col];
#pragma unroll
        for (int mt = 0; mt < 4; ++mt) {
            const int rowb = m0 + wr + mt * 16 + quad * 4;
#pragma unroll
            for (int r = 0; r < 4; ++r) {
                if (OUT_F32)
                    ((float*)Cout)[(size_t)(rowb + r) * N + col] = acc[mt][nt][r] + bv;
                else
                    ((unsigned short*)Cout)[(size_t)(rowb + r) * N + col] =
                        f2bf(acc[mt][nt][r] + bv);
            }
        }
    }
}

// ---------------- windowed attention, flash-style ----------------
// qkv: [R,3072] bf16 (Q|K|V, head h at cols h*64). O: [R,1024] bf16.
// Block = (window-instance, head, 64-row q-tile); 4 waves x 16 q-rows.
// K-tiles of 128 keys; online softmax; mask adds +1.0 (NOT -inf) for j>i.
__global__ __launch_bounds__(256) void attn_win(const unsigned short* __restrict__ qkv,
                                                unsigned short* __restrict__ O,
                                                int W) {
    const int nq = W >> 6;           // q-tiles per window
    const int nkt = W >> 7;          // 128-key tiles per window
    const int tid = threadIdx.x, wv = tid >> 6, lane = tid & 63;
    const int quad = lane >> 4, l16 = lane & 15;
    const int hq = 16 * nq;
    const int winst = blockIdx.x / hq;
    const int rem = blockIdx.x - winst * hq;
    const int head = rem / nq, qt = rem - head * nq;
    const size_t rw = (size_t)winst * W;

    __shared__ unsigned short Ks[128 * 72];        // [key][64+8 pad]
    __shared__ unsigned short Vs[64 * 136];        // V^T: [dh][128+8 pad]
    __shared__ unsigned short Ps[4 * 16 * 136];    // per-wave P: [16 rows][128+8]

    // Q A-frags direct from global (A[m=lane&15][k=quad*8+j]); reused all K-tiles
    v8s qf[2];
    {
        const size_t qrow = rw + (size_t)(qt * 64 + wv * 16 + l16);
        const unsigned short* qp = qkv + qrow * 3072 + head * 64 + quad * 8;
        qf[0] = *(const v8s*)qp;
        qf[1] = *(const v8s*)(qp + 32);
    }
    float mold[4], lsum[4];
    v4f oacc[4] = {};
#pragma unroll
    for (int r = 0; r < 4; ++r) { mold[r] = -1e30f; lsum[r] = 0.0f; }

    const int ibase = qt * 64 + wv * 16 + quad * 4;   // window-local q row base (per reg r)
    const int pbase = wv * 16 * 136;

    for (int kt = 0; kt < nkt; ++kt) {
        __syncthreads();
        // stage K (row-major padded) and V (transposed) for this 128-key tile
#pragma unroll
        for (int it = 0; it < 4; ++it) {
            const int t = tid + it * 256;
            const int key = t >> 3, ch = t & 7;
            const unsigned short* kp =
                qkv + (rw + (size_t)(kt * 128 + key)) * 3072 + 1024 + head * 64 + ch * 8;
            *(v8s*)(Ks + key * 72 + ch * 8) = *(const v8s*)kp;
            const v8s vv = *(const v8s*)(kp + 1024);   // V at col offset 2048
#pragma unroll
            for (int j = 0; j < 8; ++j)
                Vs[(ch * 8 + j) * 136 + key] = ((const unsigned short*)&vv)[j];
        }
        __syncthreads();

        // S = Q K^T : wave's 16 rows x 128 keys (8 col-tiles), K=64 in 2 MFMA steps
        v4f sf[8] = {};
#pragma unroll
        for (int ks = 0; ks < 2; ++ks)
#pragma unroll
            for (int nt = 0; nt < 8; ++nt) {
                const v8s kf = *(const v8s*)(Ks + (nt * 16 + l16) * 72 + ks * 32 + quad * 8);
                sf[nt] = __builtin_amdgcn_mfma_f32_16x16x32_bf16(qf[ks], kf, sf[nt], 0, 0, 0);
            }

        // scale + additive mask + online softmax (rows live in 16-lane quads)
        float pv[8][4];
#pragma unroll
        for (int r = 0; r < 4; ++r) {
            const int i = ibase + r;
            float mx = -1e30f;
#pragma unroll
            for (int nt = 0; nt < 8; ++nt) {
                const int j = kt * 128 + nt * 16 + l16;
                const float s = sf[nt][r] * 0.125f + ((j > i) ? 1.0f : 0.0f);
                pv[nt][r] = s;
                mx = fmaxf(mx, s);
            }
            mx = fmaxf(mx, __shfl_xor(mx, 1));
            mx = fmaxf(mx, __shfl_xor(mx, 2));
            mx = fmaxf(mx, __shfl_xor(mx, 4));
            mx = fmaxf(mx, __shfl_xor(mx, 8));
            const float mn = fmaxf(mold[r], mx);
            const float alpha = __expf(mold[r] - mn);
            float rs = 0.0f;
#pragma unroll
            for (int nt = 0; nt < 8; ++nt) {
                const float e = __expf(pv[nt][r] - mn);
                pv[nt][r] = e;
                rs += e;
            }
            rs += __shfl_xor(rs, 1);
            rs += __shfl_xor(rs, 2);
            rs += __shfl_xor(rs, 4);
            rs += __shfl_xor(rs, 8);
            lsum[r] = lsum[r] * alpha + rs;
            mold[r] = mn;
#pragma unroll
            for (int dt = 0; dt < 4; ++dt) oacc[dt][r] *= alpha;
        }

        // P: C-layout regs -> LDS -> A-layout (m120-verified transform)
#pragma unroll
        for (int nt = 0; nt < 8; ++nt)
#pragma unroll
            for (int r = 0; r < 4; ++r)
                Ps[pbase + (quad * 4 + r) * 136 + nt * 16 + l16] = f2bf(pv[nt][r]);
        __syncthreads();

        // O += P V : K=128 keys in 4 MFMA steps, 4 dh tiles
#pragma unroll
        for (int kk = 0; kk < 4; ++kk) {
            const v8s pf = *(const v8s*)(Ps + pbase + l16 * 136 + kk * 32 + quad * 8);
#pragma unroll
            for (int dt = 0; dt < 4; ++dt) {
                const v8s vf = *(const v8s*)(Vs + (dt * 16 + l16) * 136 + kk * 32 + quad * 8);
                oacc[dt] = __builtin_amdgcn_mfma_f32_16x16x32_bf16(pf, vf, oacc[dt], 0, 0, 0);
            }
        }
    }

    // normalize + store O (bf16)
#pragma unroll
    for (int dt = 0; dt < 4; ++dt) {
        const int col = head * 64 + dt * 16 + l16;
#pragma unroll
        for (int r = 0; r < 4; ++r) {
            const size_t row = rw + (size_t)(ibase + r);
            O[row * 1024 + col] = f2bf(oacc[dt][r] / lsum[r]);
        }
    }
}

// ---------------- launcher ----------------
extern "C" void kernel_launch(void* const* d_in, const int* in_sizes, int n_in,
                              void* d_out, int out_size, void* d_ws, size_t ws_size,
                              hipStream_t stream) {
    const float* lqs    = (const float*)d_in[0];
    const float* gqs    = (const float*)d_in[1];
    const float* wl_in  = (const float*)d_in[2];
    const float* bl_in  = (const float*)d_in[3];
    const float* wl_out = (const float*)d_in[4];
    const float* bl_out = (const float*)d_in[5];
    const float* wg_in  = (const float*)d_in[6];
    const float* bg_in  = (const float*)d_in[7];
    const float* wg_out = (const float*)d_in[8];
    const float* bg_out = (const float*)d_in[9];

    char* ws = (char*)d_ws;                                      // peak use: 176,160,768 B
    unsigned short* Xbf    = (unsigned short*)(ws);              // 33,554,432
    unsigned short* Obf    = (unsigned short*)(ws + 33554432);   // 33,554,432
    unsigned short* Winbf  = (unsigned short*)(ws + 67108864);   //  6,291,456
    unsigned short* Woutbf = (unsigned short*)(ws + 73400320);   //  2,097,152
    unsigned short* QKVbf  = (unsigned short*)(ws + 75497472);   // 100,663,296

    const int R = 4 * 4096;   // 16384 rows total (windows tile S contiguously)
    const int D = 1024;

    for (int path = 0; path < 2; ++path) {
        const float* x     = path == 0 ? lqs : gqs;
        const float* w_in  = path == 0 ? wl_in : wg_in;
        const float* b_in  = path == 0 ? bl_in : bg_in;
        const float* w_out = path == 0 ? wl_out : wg_out;
        const float* b_out = path == 0 ? bl_out : bg_out;
        const int W        = path == 0 ? 128 : 1024;
        float* outp = (float*)d_out + (size_t)path * R * D;

        hipLaunchKernelGGL(cast_f32_bf16, dim3(4096), dim3(256), 0, stream, x, Xbf, R * D);
        hipLaunchKernelGGL(cast_f32_bf16, dim3(3072), dim3(256), 0, stream, w_in, Winbf, 3 * D * D);
        hipLaunchKernelGGL(cast_f32_bf16, dim3(1024), dim3(256), 0, stream, w_out, Woutbf, D * D);
        hipLaunchKernelGGL((gemm_nt<false>), dim3(128 * 24), dim3(256), 0, stream,
                           Xbf, Winbf, b_in, (void*)QKVbf, R, 3 * D, D);
        hipLaunchKernelGGL(attn_win, dim3(4096), dim3(256), 0, stream, QKVbf, Obf, W);
        hipLaunchKernelGGL((gemm_nt<true>), dim3(128 * 8), dim3(256), 0, stream,
                           Obf, Woutbf, b_out, (void*)outp, R, D, D);
    }
}

// Round 2
// 818.186 us; speedup vs baseline: 1.1740x; 1.1740x over previous
//
#include <hip/hip_runtime.h>
#include <stdint.h>

typedef short v8s __attribute__((ext_vector_type(8)));   // 8 bf16 (4 VGPRs)
typedef float v4f __attribute__((ext_vector_type(4)));   // 16x16 C/D frag

__device__ __forceinline__ unsigned short f2bf(float f) {
    union { float f; uint32_t u; } x; x.f = f;
    uint32_t r = (x.u + 0x7fffu + ((x.u >> 16) & 1u)) >> 16;
    return (unsigned short)r;
}

// ---------------- fp32 -> bf16 cast (memory-bound) ----------------
__global__ __launch_bounds__(256) void cast_f32_bf16(const float* __restrict__ in,
                                                     unsigned short* __restrict__ out, int n) {
    int i = (blockIdx.x * 256 + threadIdx.x) * 4;
    const int stride = gridDim.x * 256 * 4;
    for (; i < n; i += stride) {
        float4 v = *(const float4*)(in + i);
        ushort4 o;
        o.x = f2bf(v.x); o.y = f2bf(v.y); o.z = f2bf(v.z); o.w = f2bf(v.w);
        *(ushort4*)(out + i) = o;
    }
}

// ---------------- NT GEMM: C[M,N] = A[M,K] * B[N,K]^T + bias ----------------
// 128x128 tile, BK=64, 4 waves (2x2 of 64x64), 16x16x32 bf16 MFMA,
// global_load_lds width-16 staging, XOR-swizzled 16B chunks.
// VSPLIT: cols >= 2048 (the V third of QKV) are written TRANSPOSED to vt[col-2048][M]
// (packed ushort4 along rows); cols < 2048 go row-major to Cout with stride ldc.
template <bool OUT_F32, bool VSPLIT>
__global__ __launch_bounds__(256) void gemm_nt(const unsigned short* __restrict__ A,
                                               const unsigned short* __restrict__ B,
                                               const float* __restrict__ bias,
                                               void* __restrict__ Cout,
                                               unsigned short* __restrict__ vt,
                                               int M, int N, int K, int ldc) {
    __shared__ unsigned short As[128 * 64];
    __shared__ unsigned short Bs[128 * 64];
    const int tid = threadIdx.x;
    const int wv = tid >> 6, lane = tid & 63;
    const int quad = lane >> 4, l16 = lane & 15;
    const int tiles_n = N >> 7;
    const int tm = blockIdx.x / tiles_n, tn = blockIdx.x - tm * tiles_n;
    const int m0 = tm << 7, n0 = tn << 7;
    const int wr = (wv >> 1) * 64, wc = (wv & 1) * 64;

    v4f acc[4][4] = {};

    for (int k0 = 0; k0 < K; k0 += 64) {
        __syncthreads();
#pragma unroll
        for (int j = 0; j < 4; ++j) {
            const int cb = (wv * 4 + j) * 64;          // wave-uniform chunk base
            const int cl = cb + lane;
            const int row = cl >> 3;
            const int kc = (cl & 7) ^ (row & 7);       // swizzled source chunk
            const unsigned short* ga = A + (size_t)(m0 + row) * K + k0 + kc * 8;
            const unsigned short* gb = B + (size_t)(n0 + row) * K + k0 + kc * 8;
            __builtin_amdgcn_global_load_lds(
                (const __attribute__((address_space(1))) unsigned int*)ga,
                (__attribute__((address_space(3))) unsigned int*)(As + cb * 8), 16, 0, 0);
            __builtin_amdgcn_global_load_lds(
                (const __attribute__((address_space(1))) unsigned int*)gb,
                (__attribute__((address_space(3))) unsigned int*)(Bs + cb * 8), 16, 0, 0);
        }
        __syncthreads();
#pragma unroll
        for (int ks = 0; ks < 2; ++ks) {
            v8s af[4], bf[4];
#pragma unroll
            for (int mt = 0; mt < 4; ++mt) {
                const int row = wr + mt * 16 + l16;
                const int ch = row * 8 + ((ks * 4 + quad) ^ (row & 7));
                af[mt] = *(const v8s*)(As + ch * 8);
            }
#pragma unroll
            for (int nt = 0; nt < 4; ++nt) {
                const int row = wc + nt * 16 + l16;
                const int ch = row * 8 + ((ks * 4 + quad) ^ (row & 7));
                bf[nt] = *(const v8s*)(Bs + ch * 8);
            }
#pragma unroll
            for (int mt = 0; mt < 4; ++mt)
#pragma unroll
                for (int nt = 0; nt < 4; ++nt)
                    acc[mt][nt] = __builtin_amdgcn_mfma_f32_16x16x32_bf16(
                        af[mt], bf[nt], acc[mt][nt], 0, 0, 0);
        }
    }
    // epilogue: bias + store (C/D layout: col=lane&15, row=quad*4+reg)
#pragma unroll
    for (int nt = 0; nt < 4; ++nt) {
        const int col = n0 + wc + nt * 16 + l16;
        const float bv = bias[col];
        if (VSPLIT && col >= 2048) {
            // V third: store transposed (rows of Vt are contiguous along GEMM rows)
#pragma unroll
            for (int mt = 0; mt < 4; ++mt) {
                const int rowb = m0 + wr + mt * 16 + quad * 4;
                ushort4 o;
                o.x = f2bf(acc[mt][nt][0] + bv);
                o.y = f2bf(acc[mt][nt][1] + bv);
                o.z = f2bf(acc[mt][nt][2] + bv);
                o.w = f2bf(acc[mt][nt][3] + bv);
                *(ushort4*)(vt + (size_t)(col - 2048) * M + rowb) = o;
            }
        } else {
#pragma unroll
            for (int mt = 0; mt < 4; ++mt) {
                const int rowb = m0 + wr + mt * 16 + quad * 4;
#pragma unroll
                for (int r = 0; r < 4; ++r) {
                    if (OUT_F32)
                        ((float*)Cout)[(size_t)(rowb + r) * ldc + col] = acc[mt][nt][r] + bv;
                    else
                        ((unsigned short*)Cout)[(size_t)(rowb + r) * ldc + col] =
                            f2bf(acc[mt][nt][r] + bv);
                }
            }
        }
    }
}

// ---------------- windowed attention ----------------
// qk: [R,2048] bf16 (Q|K, head h at cols h*64 / 1024+h*64). Vt: [1024][R] bf16 (V^T).
// O: [R,1024] bf16. Block = (window, head, 128-row q-block); 4 waves x 2 subtiles x 16 rows.
// K-tiles of 128 keys staged via global_load_lds (XOR chunk swizzle, conflict-free).
// No online softmax: mask is +1.0 (not -inf) and scores are bounded, so shift=0 is exact.
__global__ __launch_bounds__(256, 3) void attn_win(const unsigned short* __restrict__ qk,
                                                   const unsigned short* __restrict__ Vt,
                                                   unsigned short* __restrict__ O,
                                                   int W) {
    const int nkt = W >> 7;                 // 128-key tiles per window (== q-blocks)
    const int tid = threadIdx.x, wv = tid >> 6, lane = tid & 63;
    const int quad = lane >> 4, l16 = lane & 15;
    const int hq = 16 * nkt;
    const int winst = blockIdx.x / hq;
    const int rem = blockIdx.x - winst * hq;
    const int head = rem / nkt, qb = rem - head * nkt;
    const size_t rw = (size_t)winst * W;

    __shared__ unsigned short Ks[128 * 64];     // [key][8 chunks, XOR-swizzled]
    __shared__ unsigned short Vs[64 * 128];     // [dh][16 chunks, XOR-swizzled] (V^T tile)
    __shared__ unsigned short Ps[4 * 16 * 128]; // per-wave P, chunk-swizzled
    unsigned short* Pw = Ps + wv * 16 * 128;

    // Q A-frags from global, reused across all K-tiles: [subtile][ks]
    v8s qf[2][2];
#pragma unroll
    for (int st = 0; st < 2; ++st) {
        const size_t qrow = rw + (size_t)(qb * 128 + wv * 32 + st * 16 + l16);
        const unsigned short* qp = qk + qrow * 2048 + head * 64 + quad * 8;
        qf[st][0] = *(const v8s*)qp;
        qf[st][1] = *(const v8s*)(qp + 32);
    }

    float rs[2][4] = {};    // per-lane partial row sums (reduced across l16 at the end)
    v4f oacc[2][4] = {};    // O accumulator, C-layout

    for (int kt = 0; kt < nkt; ++kt) {
        __syncthreads();    // prior tile's LDS reads done
#pragma unroll
        for (int j = 0; j < 4; ++j) {           // stage K tile: 128 keys x 64 dh
            const int cb = (wv * 4 + j) * 64;
            const int cl = cb + lane;
            const int key = cl >> 3, c = cl & 7;
            const unsigned short* src = qk + (rw + (size_t)(kt * 128 + key)) * 2048
                                        + 1024 + head * 64 + ((c ^ (key & 7)) * 8);
            __builtin_amdgcn_global_load_lds(
                (const __attribute__((address_space(1))) unsigned int*)src,
                (__attribute__((address_space(3))) unsigned int*)(Ks + cb * 8), 16, 0, 0);
        }
#pragma unroll
        for (int j = 0; j < 4; ++j) {           // stage V^T tile: 64 dh x 128 keys
            const int cb = (wv * 4 + j) * 64;
            const int cl = cb + lane;
            const int dh = cl >> 4, c = cl & 15;
            const unsigned short* src = Vt + (size_t)(head * 64 + dh) * 16384
                                        + rw + (size_t)(kt * 128) + ((c ^ (dh & 7)) * 8);
            __builtin_amdgcn_global_load_lds(
                (const __attribute__((address_space(1))) unsigned int*)src,
                (__attribute__((address_space(3))) unsigned int*)(Vs + cb * 8), 16, 0, 0);
        }
        __syncthreads();    // drains vmcnt: tiles resident

#pragma unroll
        for (int st = 0; st < 2; ++st) {
            // S = Q K^T : 16 q-rows x 128 keys
            v4f sf[8] = {};
#pragma unroll
            for (int ks = 0; ks < 2; ++ks)
#pragma unroll
                for (int nt = 0; nt < 8; ++nt) {
                    const int krow = nt * 16 + l16;
                    const v8s kf = *(const v8s*)(Ks + krow * 64 + ((ks * 4 + quad) ^ (krow & 7)) * 8);
                    sf[nt] = __builtin_amdgcn_mfma_f32_16x16x32_bf16(qf[st][ks], kf, sf[nt], 0, 0, 0);
                }
            // scale + additive mask + exp (no shift: scores bounded), write P (bf16)
            const int ibase = qb * 128 + wv * 32 + st * 16 + quad * 4;
#pragma unroll
            for (int r = 0; r < 4; ++r) {
                const int i = ibase + r;
                const int prow = quad * 4 + r;
#pragma unroll
                for (int nt = 0; nt < 8; ++nt) {
                    const int j = kt * 128 + nt * 16 + l16;
                    const float e = __expf(sf[nt][r] * 0.125f + ((j > i) ? 1.0f : 0.0f));
                    rs[st][r] += e;
                    const int sch = (nt * 2 + (l16 >> 3)) ^ (prow & 7);
                    Pw[prow * 128 + sch * 8 + (l16 & 7)] = f2bf(e);
                }
            }
            // P is wave-private; same-wave DS ops are processed in order -> no barrier.
            // O += P V : K=128 keys in 4 MFMA steps, 4 dh tiles
#pragma unroll
            for (int kk = 0; kk < 4; ++kk) {
                const v8s pf = *(const v8s*)(Pw + l16 * 128 + ((kk * 4 + quad) ^ (l16 & 7)) * 8);
#pragma unroll
                for (int dt = 0; dt < 4; ++dt) {
                    const int dh = dt * 16 + l16;
                    const v8s vf = *(const v8s*)(Vs + dh * 128 + ((kk * 4 + quad) ^ (dh & 7)) * 8);
                    oacc[st][dt] = __builtin_amdgcn_mfma_f32_16x16x32_bf16(pf, vf, oacc[st][dt], 0, 0, 0);
                }
            }
        }
    }

    // reduce row sums across the 16 lanes holding each row, normalize, store
#pragma unroll
    for (int st = 0; st < 2; ++st)
#pragma unroll
        for (int r = 0; r < 4; ++r) {
            float l = rs[st][r];
            l += __shfl_xor(l, 1);
            l += __shfl_xor(l, 2);
            l += __shfl_xor(l, 4);
            l += __shfl_xor(l, 8);
            const float inv = 1.0f / l;
            const size_t row = rw + (size_t)(qb * 128 + wv * 32 + st * 16 + quad * 4 + r);
#pragma unroll
            for (int dt = 0; dt < 4; ++dt)
                O[row * 1024 + head * 64 + dt * 16 + l16] = f2bf(oacc[st][dt][r] * inv);
        }
}

// ---------------- launcher ----------------
extern "C" void kernel_launch(void* const* d_in, const int* in_sizes, int n_in,
                              void* d_out, int out_size, void* d_ws, size_t ws_size,
                              hipStream_t stream) {
    const float* lqs    = (const float*)d_in[0];
    const float* gqs    = (const float*)d_in[1];
    const float* wl_in  = (const float*)d_in[2];
    const float* bl_in  = (const float*)d_in[3];
    const float* wl_out = (const float*)d_in[4];
    const float* bl_out = (const float*)d_in[5];
    const float* wg_in  = (const float*)d_in[6];
    const float* bg_in  = (const float*)d_in[7];
    const float* wg_out = (const float*)d_in[8];
    const float* bg_out = (const float*)d_in[9];

    char* ws = (char*)d_ws;                                       // total 176,160,768 B
    unsigned short* Xbf    = (unsigned short*)(ws);               // 33,554,432
    unsigned short* Obf    = (unsigned short*)(ws + 33554432);    // 33,554,432
    unsigned short* Winbf  = (unsigned short*)(ws + 67108864);    //  6,291,456
    unsigned short* Woutbf = (unsigned short*)(ws + 73400320);    //  2,097,152
    unsigned short* QKbf   = (unsigned short*)(ws + 75497472);    // 67,108,864  [R][2048]
    unsigned short* Vtbf   = (unsigned short*)(ws + 142606336);   // 33,554,432  [1024][R]

    const int R = 4 * 4096;   // 16384 rows (windows tile S contiguously)
    const int D = 1024;

    for (int path = 0; path < 2; ++path) {
        const float* x     = path == 0 ? lqs : gqs;
        const float* w_in  = path == 0 ? wl_in : wg_in;
        const float* b_in  = path == 0 ? bl_in : bg_in;
        const float* w_out = path == 0 ? wl_out : wg_out;
        const float* b_out = path == 0 ? bl_out : bg_out;
        const int W        = path == 0 ? 128 : 1024;
        float* outp = (float*)d_out + (size_t)path * R * D;

        hipLaunchKernelGGL(cast_f32_bf16, dim3(4096), dim3(256), 0, stream, x, Xbf, R * D);
        hipLaunchKernelGGL(cast_f32_bf16, dim3(3072), dim3(256), 0, stream, w_in, Winbf, 3 * D * D);
        hipLaunchKernelGGL(cast_f32_bf16, dim3(1024), dim3(256), 0, stream, w_out, Woutbf, D * D);
        // QKV projection: Q|K row-major (ldc=2048), V transposed into Vtbf
        hipLaunchKernelGGL((gemm_nt<false, true>), dim3(128 * 24), dim3(256), 0, stream,
                           Xbf, Winbf, b_in, (void*)QKbf, Vtbf, R, 3 * D, D, 2048);
        hipLaunchKernelGGL(attn_win, dim3(2048), dim3(256), 0, stream, QKbf, Vtbf, Obf, W);
        // output projection -> fp32 d_out
        hipLaunchKernelGGL((gemm_nt<true, false>), dim3(128 * 8), dim3(256), 0, stream,
                           Obf, Woutbf, b_out, (void*)outp, (unsigned short*)nullptr,
                           R, D, D, 1024);
    }
}

// Round 3
// 764.135 us; speedup vs baseline: 1.2570x; 1.0707x over previous
//
#include <hip/hip_runtime.h>
#include <stdint.h>

typedef short v8s __attribute__((ext_vector_type(8)));   // 8 bf16 (4 VGPRs)
typedef float v4f __attribute__((ext_vector_type(4)));   // 16x16 C/D frag

__device__ __forceinline__ unsigned short f2bf(float f) {
    union { float f; uint32_t u; } x; x.f = f;
    uint32_t r = (x.u + 0x7fffu + ((x.u >> 16) & 1u)) >> 16;
    return (unsigned short)r;
}
__device__ __forceinline__ uint32_t pack_bf2(float lo, float hi) {
    union { float f; uint32_t u; } a, b; a.f = lo; b.f = hi;
    uint32_t rl = (a.u + 0x7fffu + ((a.u >> 16) & 1u)) >> 16;
    uint32_t rh = (b.u + 0x7fffu + ((b.u >> 16) & 1u)) & 0xffff0000u;
    return rh | rl;
}

// ---------------- fp32 -> bf16 cast (memory-bound) ----------------
__global__ __launch_bounds__(256) void cast_f32_bf16(const float* __restrict__ in,
                                                     unsigned short* __restrict__ out, int n) {
    int i = (blockIdx.x * 256 + threadIdx.x) * 4;
    const int stride = gridDim.x * 256 * 4;
    for (; i < n; i += stride) {
        float4 v = *(const float4*)(in + i);
        ushort4 o;
        o.x = f2bf(v.x); o.y = f2bf(v.y); o.z = f2bf(v.z); o.w = f2bf(v.w);
        *(ushort4*)(out + i) = o;
    }
}

// ---------------- NT GEMM: C[M,N] = A[M,K] * B[N,K]^T + bias ----------------
// 128x128 tile, BK=64, 4 waves (2x2 of 64x64), 16x16x32 bf16 MFMA,
// global_load_lds width-16 staging, XOR-swizzled 16B chunks.
// VSPLIT: cols >= 2048 (V third of QKV) stored TRANSPOSED to vt[col-2048][M].
template <bool OUT_F32, bool VSPLIT>
__global__ __launch_bounds__(256) void gemm_nt(const unsigned short* __restrict__ A,
                                               const unsigned short* __restrict__ B,
                                               const float* __restrict__ bias,
                                               void* __restrict__ Cout,
                                               unsigned short* __restrict__ vt,
                                               int M, int N, int K, int ldc) {
    __shared__ unsigned short As[128 * 64];
    __shared__ unsigned short Bs[128 * 64];
    const int tid = threadIdx.x;
    const int wv = tid >> 6, lane = tid & 63;
    const int quad = lane >> 4, l16 = lane & 15;
    const int tiles_n = N >> 7;
    const int tm = blockIdx.x / tiles_n, tn = blockIdx.x - tm * tiles_n;
    const int m0 = tm << 7, n0 = tn << 7;
    const int wr = (wv >> 1) * 64, wc = (wv & 1) * 64;

    v4f acc[4][4] = {};

    for (int k0 = 0; k0 < K; k0 += 64) {
        __syncthreads();
#pragma unroll
        for (int j = 0; j < 4; ++j) {
            const int cb = (wv * 4 + j) * 64;
            const int cl = cb + lane;
            const int row = cl >> 3;
            const int kc = (cl & 7) ^ (row & 7);
            const unsigned short* ga = A + (size_t)(m0 + row) * K + k0 + kc * 8;
            const unsigned short* gb = B + (size_t)(n0 + row) * K + k0 + kc * 8;
            __builtin_amdgcn_global_load_lds(
                (const __attribute__((address_space(1))) unsigned int*)ga,
                (__attribute__((address_space(3))) unsigned int*)(As + cb * 8), 16, 0, 0);
            __builtin_amdgcn_global_load_lds(
                (const __attribute__((address_space(1))) unsigned int*)gb,
                (__attribute__((address_space(3))) unsigned int*)(Bs + cb * 8), 16, 0, 0);
        }
        __syncthreads();
#pragma unroll
        for (int ks = 0; ks < 2; ++ks) {
            v8s af[4], bf[4];
#pragma unroll
            for (int mt = 0; mt < 4; ++mt) {
                const int row = wr + mt * 16 + l16;
                const int ch = row * 8 + ((ks * 4 + quad) ^ (row & 7));
                af[mt] = *(const v8s*)(As + ch * 8);
            }
#pragma unroll
            for (int nt = 0; nt < 4; ++nt) {
                const int row = wc + nt * 16 + l16;
                const int ch = row * 8 + ((ks * 4 + quad) ^ (row & 7));
                bf[nt] = *(const v8s*)(Bs + ch * 8);
            }
#pragma unroll
            for (int mt = 0; mt < 4; ++mt)
#pragma unroll
                for (int nt = 0; nt < 4; ++nt)
                    acc[mt][nt] = __builtin_amdgcn_mfma_f32_16x16x32_bf16(
                        af[mt], bf[nt], acc[mt][nt], 0, 0, 0);
        }
    }
#pragma unroll
    for (int nt = 0; nt < 4; ++nt) {
        const int col = n0 + wc + nt * 16 + l16;
        const float bv = bias[col];
        if (VSPLIT && col >= 2048) {
#pragma unroll
            for (int mt = 0; mt < 4; ++mt) {
                const int rowb = m0 + wr + mt * 16 + quad * 4;
                ushort4 o;
                o.x = f2bf(acc[mt][nt][0] + bv);
                o.y = f2bf(acc[mt][nt][1] + bv);
                o.z = f2bf(acc[mt][nt][2] + bv);
                o.w = f2bf(acc[mt][nt][3] + bv);
                *(ushort4*)(vt + (size_t)(col - 2048) * M + rowb) = o;
            }
        } else {
#pragma unroll
            for (int mt = 0; mt < 4; ++mt) {
                const int rowb = m0 + wr + mt * 16 + quad * 4;
#pragma unroll
                for (int r = 0; r < 4; ++r) {
                    if (OUT_F32)
                        ((float*)Cout)[(size_t)(rowb + r) * ldc + col] = acc[mt][nt][r] + bv;
                    else
                        ((unsigned short*)Cout)[(size_t)(rowb + r) * ldc + col] =
                            f2bf(acc[mt][nt][r] + bv);
                }
            }
        }
    }
}

// ---------------- windowed attention (S^T orientation) ----------------
// qk: [R,2048] bf16 (Q|K). Vt: [1024][R] bf16 (V^T). O: [R,1024] bf16.
// Block = (window, head, 128-row q-block); wave = 32 q-rows (2 subtiles).
// S^T = K*Q^T via MFMA(A=K-frag, B=Q-frag): C-layout puts 4 CONSECUTIVE keys
// (quad*4+r) of one q-row (l16) in each lane -> P written as packed ds_write_b64
// straight into A-operand layout. K-frag LDS reads shared across both subtiles.
// No online softmax (mask is +1.0 additive, scores bounded -> shift=0 exact).
__global__ __launch_bounds__(256, 3) void attn_win(const unsigned short* __restrict__ qk,
                                                   const unsigned short* __restrict__ Vt,
                                                   unsigned short* __restrict__ O,
                                                   int W) {
    const int nkt = W >> 7;
    const int tid = threadIdx.x, wv = tid >> 6, lane = tid & 63;
    const int quad = lane >> 4, l16 = lane & 15;

    // block remap (global path): keep the 8 q-blocks of one (window,head) on one XCD
    int wh, qb;
    if (nkt == 8) {
        const int g = blockIdx.x;
        wh = (g >> 6) * 8 + (g & 7);     // window*16+head
        qb = (g >> 3) & 7;
    } else {
        wh = blockIdx.x; qb = 0;
    }
    const int winst = wh >> 4, head = wh & 15;
    const size_t rw = (size_t)winst * W;

    __shared__ unsigned short Ks[128 * 64];     // [key][8 chunks, XOR-swizzled]
    __shared__ unsigned short Vs[64 * 128];     // V^T tile [dh][16 chunks, XOR-swizzled]
    __shared__ unsigned short Ps[4 * 16 * 136]; // per-wave P [16 q-rows][128 keys + 8 pad]
    unsigned short* Pw = Ps + wv * 16 * 136;

    // Q frags (B-operand layout: lane&15 = q-row, quad*8+j = k), reused all k-tiles
    v8s qf[2][2];
#pragma unroll
    for (int st = 0; st < 2; ++st) {
        const size_t qrow = rw + (size_t)(qb * 128 + wv * 32 + st * 16 + l16);
        const unsigned short* qp = qk + qrow * 2048 + head * 64 + quad * 8;
        qf[st][0] = *(const v8s*)qp;
        qf[st][1] = *(const v8s*)(qp + 32);
    }

    float rsum[2] = {0.f, 0.f};   // row sum for q-row l16 (partial over this lane's keys)
    v4f oacc[2][4] = {};          // O C-layout: col(dh)=l16, row(q)=quad*4+r

    for (int kt = 0; kt < nkt; ++kt) {
        __syncthreads();
#pragma unroll
        for (int j = 0; j < 4; ++j) {           // stage K tile: 128 keys x 64 dh
            const int cb = (wv * 4 + j) * 64;
            const int cl = cb + lane;
            const int key = cl >> 3, c = cl & 7;
            const unsigned short* src = qk + (rw + (size_t)(kt * 128 + key)) * 2048
                                        + 1024 + head * 64 + ((c ^ (key & 7)) * 8);
            __builtin_amdgcn_global_load_lds(
                (const __attribute__((address_space(1))) unsigned int*)src,
                (__attribute__((address_space(3))) unsigned int*)(Ks + cb * 8), 16, 0, 0);
        }
#pragma unroll
        for (int j = 0; j < 4; ++j) {           // stage V^T tile: 64 dh x 128 keys
            const int cb = (wv * 4 + j) * 64;
            const int cl = cb + lane;
            const int dh = cl >> 4, c = cl & 15;
            const unsigned short* src = Vt + (size_t)(head * 64 + dh) * 16384
                                        + rw + (size_t)(kt * 128) + ((c ^ (dh & 7)) * 8);
            __builtin_amdgcn_global_load_lds(
                (const __attribute__((address_space(1))) unsigned int*)src,
                (__attribute__((address_space(3))) unsigned int*)(Vs + cb * 8), 16, 0, 0);
        }
        __syncthreads();

        // S^T for both subtiles, sharing every K-frag read
        v4f sf[2][8] = {};
#pragma unroll
        for (int nt = 0; nt < 8; ++nt) {
            const int krow = nt * 16 + l16;
#pragma unroll
            for (int ks = 0; ks < 2; ++ks) {
                const v8s kf = *(const v8s*)(Ks + krow * 64 + ((ks * 4 + quad) ^ (krow & 7)) * 8);
                sf[0][nt] = __builtin_amdgcn_mfma_f32_16x16x32_bf16(kf, qf[0][ks], sf[0][nt], 0, 0, 0);
                sf[1][nt] = __builtin_amdgcn_mfma_f32_16x16x32_bf16(kf, qf[1][ks], sf[1][nt], 0, 0, 0);
            }
        }

#pragma unroll
        for (int st = 0; st < 2; ++st) {
            const int irow = qb * 128 + wv * 32 + st * 16 + l16;   // this lane's q-row
            float rl = 0.f;
#pragma unroll
            for (int nt = 0; nt < 8; ++nt) {
                const int jb = kt * 128 + nt * 16 + quad * 4;      // first key in this lane's 4
                float e[4];
#pragma unroll
                for (int r = 0; r < 4; ++r)
                    e[r] = __expf(fmaf(sf[st][nt][r], 0.125f, (jb + r > irow) ? 1.0f : 0.0f));
                rl += (e[0] + e[1]) + (e[2] + e[3]);
                uint2 pk;
                pk.x = pack_bf2(e[0], e[1]);
                pk.y = pack_bf2(e[2], e[3]);
                *(uint2*)(Pw + l16 * 136 + nt * 16 + quad * 4) = pk;   // ds_write_b64
            }
            rsum[st] += rl;
            // O += P V  (P read back in A-layout; same-wave DS ordering, no barrier)
#pragma unroll
            for (int kk = 0; kk < 4; ++kk) {
                const v8s pf = *(const v8s*)(Pw + l16 * 136 + kk * 32 + quad * 8);
#pragma unroll
                for (int dt = 0; dt < 4; ++dt) {
                    const int dh = dt * 16 + l16;
                    const v8s vf = *(const v8s*)(Vs + dh * 128 + ((kk * 4 + quad) ^ (dh & 7)) * 8);
                    oacc[st][dt] = __builtin_amdgcn_mfma_f32_16x16x32_bf16(pf, vf, oacc[st][dt], 0, 0, 0);
                }
            }
        }
    }

    // reduce row sums across quads (row = l16), redistribute to C-layout rows, store
#pragma unroll
    for (int st = 0; st < 2; ++st) {
        float l = rsum[st];
        l += __shfl_xor(l, 16);
        l += __shfl_xor(l, 32);
        const float inv = 1.0f / l;              // inverse sum for q-row l16
#pragma unroll
        for (int r = 0; r < 4; ++r) {
            const float invr = __shfl(inv, quad * 4 + r);   // row quad*4+r's inverse
            const size_t row = rw + (size_t)(qb * 128 + wv * 32 + st * 16 + quad * 4 + r);
#pragma unroll
            for (int dt = 0; dt < 4; ++dt)
                O[row * 1024 + head * 64 + dt * 16 + l16] = f2bf(oacc[st][dt][r] * invr);
        }
    }
}

// ---------------- launcher ----------------
extern "C" void kernel_launch(void* const* d_in, const int* in_sizes, int n_in,
                              void* d_out, int out_size, void* d_ws, size_t ws_size,
                              hipStream_t stream) {
    const float* lqs    = (const float*)d_in[0];
    const float* gqs    = (const float*)d_in[1];
    const float* wl_in  = (const float*)d_in[2];
    const float* bl_in  = (const float*)d_in[3];
    const float* wl_out = (const float*)d_in[4];
    const float* bl_out = (const float*)d_in[5];
    const float* wg_in  = (const float*)d_in[6];
    const float* bg_in  = (const float*)d_in[7];
    const float* wg_out = (const float*)d_in[8];
    const float* bg_out = (const float*)d_in[9];

    char* ws = (char*)d_ws;                                       // total 176,160,768 B
    unsigned short* Xbf    = (unsigned short*)(ws);               // 33,554,432
    unsigned short* Obf    = (unsigned short*)(ws + 33554432);    // 33,554,432
    unsigned short* Winbf  = (unsigned short*)(ws + 67108864);    //  6,291,456
    unsigned short* Woutbf = (unsigned short*)(ws + 73400320);    //  2,097,152
    unsigned short* QKbf   = (unsigned short*)(ws + 75497472);    // 67,108,864  [R][2048]
    unsigned short* Vtbf   = (unsigned short*)(ws + 142606336);   // 33,554,432  [1024][R]

    const int R = 4 * 4096;   // 16384 rows (windows tile S contiguously)
    const int D = 1024;

    for (int path = 0; path < 2; ++path) {
        const float* x     = path == 0 ? lqs : gqs;
        const float* w_in  = path == 0 ? wl_in : wg_in;
        const float* b_in  = path == 0 ? bl_in : bg_in;
        const float* w_out = path == 0 ? wl_out : wg_out;
        const float* b_out = path == 0 ? bl_out : bg_out;
        const int W        = path == 0 ? 128 : 1024;
        float* outp = (float*)d_out + (size_t)path * R * D;

        hipLaunchKernelGGL(cast_f32_bf16, dim3(4096), dim3(256), 0, stream, x, Xbf, R * D);
        hipLaunchKernelGGL(cast_f32_bf16, dim3(3072), dim3(256), 0, stream, w_in, Winbf, 3 * D * D);
        hipLaunchKernelGGL(cast_f32_bf16, dim3(1024), dim3(256), 0, stream, w_out, Woutbf, D * D);
        // QKV projection: Q|K row-major (ldc=2048), V transposed into Vtbf
        hipLaunchKernelGGL((gemm_nt<false, true>), dim3(128 * 24), dim3(256), 0, stream,
                           Xbf, Winbf, b_in, (void*)QKbf, Vtbf, R, 3 * D, D, 2048);
        hipLaunchKernelGGL(attn_win, dim3(2048), dim3(256), 0, stream, QKbf, Vtbf, Obf, W);
        // output projection -> fp32 d_out
        hipLaunchKernelGGL((gemm_nt<true, false>), dim3(128 * 8), dim3(256), 0, stream,
                           Obf, Woutbf, b_out, (void*)outp, (unsigned short*)nullptr,
                           R, D, D, 1024);
    }
}